// Round 1
// baseline (260.640 us; speedup 1.0000x reference)
//
#include <hip/hip_runtime.h>
#include <hip/hip_bf16.h>
#include <stdint.h>

#define M_B 256
#define K_D 512
#define N_C 100000
#define SCALE 64.0f

// margin constants (double-precision derived)
#define COS_M 0.87758256189037271612f
#define SIN_M 0.47942553860420300027f
#define TH   (-0.87758256189037271612f)
#define MM_C  0.23971276930210150013f

typedef __attribute__((ext_vector_type(8))) short bf16x8;
typedef __attribute__((ext_vector_type(4))) float f32x4;

// ws byte offsets
#define OFF_INVNE 0          // 256 f
#define OFF_EMB16 1024       // 256*512 ushort = 262144
#define OFF_LAB   263168     // 768 int
#define OFF_T     266240     // 768*2 f
#define OFF_ZPART 272384     // 256*1568 f = 1605632
#define OFF_ZROW  1878016    // 256 f

#define ZSTRIDE 1568
#define NCS 782   // class strips of 128: 782*128 = 100096 >= 100000

__device__ inline short f2bf(float f) {
    __hip_bfloat16 h = __float2bfloat16(f);
    return __builtin_bit_cast(short, h);
}

// ---------------- prep_emb: raw bf16 copy of E + inv row norms ----------------
__global__ __launch_bounds__(256) void prep_emb(const float* __restrict__ E,
                                                ushort* __restrict__ Eb,
                                                float* __restrict__ invne) {
    int w = threadIdx.x >> 6, lane = threadIdx.x & 63;
    int row = blockIdx.x * 4 + w;
    const float4* src = (const float4*)(E + row * K_D);
    float4 v0 = src[lane];
    float4 v1 = src[lane + 64];
    float ss = v0.x*v0.x + v0.y*v0.y + v0.z*v0.z + v0.w*v0.w
             + v1.x*v1.x + v1.y*v1.y + v1.z*v1.z + v1.w*v1.w;
    #pragma unroll
    for (int m = 32; m >= 1; m >>= 1) ss += __shfl_xor(ss, m, 64);
    ushort4 o0, o1;
    o0.x = (ushort)f2bf(v0.x); o0.y = (ushort)f2bf(v0.y);
    o0.z = (ushort)f2bf(v0.z); o0.w = (ushort)f2bf(v0.w);
    o1.x = (ushort)f2bf(v1.x); o1.y = (ushort)f2bf(v1.y);
    o1.z = (ushort)f2bf(v1.z); o1.w = (ushort)f2bf(v1.w);
    ((ushort4*)(Eb + row * K_D))[lane]      = o0;
    ((ushort4*)(Eb + row * K_D))[lane + 64] = o1;
    if (lane == 0) invne[row] = rsqrtf(ss + 1e-12f);
}

// ---------------- threefry2x32 (JAX, key=42) ----------------
__device__ inline void threefry(uint32_t x0, uint32_t x1, uint32_t& o0, uint32_t& o1) {
    const uint32_t k0 = 0u, k1 = 42u;
    const uint32_t k2 = k0 ^ k1 ^ 0x1BD11BDAu;
    const uint32_t ks[3] = {k0, k1, k2};
    x0 += k0; x1 += k1;
    const int rot0[4] = {13, 15, 26, 6};
    const int rot1[4] = {17, 29, 16, 24};
    #pragma unroll
    for (int grp = 0; grp < 5; ++grp) {
        const int* r = (grp & 1) ? rot1 : rot0;
        #pragma unroll
        for (int i = 0; i < 4; ++i) {
            x0 += x1;
            x1 = (x1 << r[i]) | (x1 >> (32 - r[i]));
            x1 ^= x0;
        }
        x0 += ks[(grp + 1) % 3];
        x1 += ks[(grp + 2) % 3] + (uint32_t)(grp + 1);
    }
    o0 = x0; o1 = x1;
}

// noise[256][8] -> stable argsort rows -> first 3 -> gather labels
__global__ void labels_kernel(const int* __restrict__ ll, int* __restrict__ lab3) {
    int b = threadIdx.x;   // 256 threads, 1 block
    float u[8];
    #pragma unroll
    for (int j = 0; j < 8; ++j) {
        int n = b * 8 + j;
        uint32_t x0, x1, o0, o1;
        if (n < 1024) { x0 = (uint32_t)n; x1 = (uint32_t)(n + 1024); }
        else          { x0 = (uint32_t)(n - 1024); x1 = (uint32_t)n; }
        threefry(x0, x1, o0, o1);
        uint32_t bits = (n < 1024) ? o0 : o1;
        uint32_t fb = (bits >> 9) | 0x3F800000u;
        u[j] = __builtin_bit_cast(float, fb) - 1.0f;
    }
    bool used[8] = {false,false,false,false,false,false,false,false};
    for (int s = 0; s < 3; ++s) {
        float bv = 2.0f; int bi = 0;
        for (int i = 0; i < 8; ++i)
            if (!used[i] && u[i] < bv) { bv = u[i]; bi = i; }
        used[bi] = true;
        lab3[b * 3 + s] = ll[b * 8 + bi];
    }
}

// ---------------- precise fp32 target cosines + margin ----------------
__global__ __launch_bounds__(256) void target_kernel(const float* __restrict__ E,
                                                     const float* __restrict__ W,
                                                     const int* __restrict__ lab3,
                                                     float* __restrict__ tp) {
    int w = threadIdx.x >> 6, lane = threadIdx.x & 63;
    int p = blockIdx.x * 4 + w;      // 768 pairs
    int b = p / 3;
    int c = lab3[p];
    const float4* ep = (const float4*)(E + (size_t)b * K_D);
    const float4* wp = (const float4*)(W + (size_t)c * K_D);
    float4 e0 = ep[lane], e1 = ep[lane + 64];
    float4 w0 = wp[lane], w1 = wp[lane + 64];
    float dot = e0.x*w0.x + e0.y*w0.y + e0.z*w0.z + e0.w*w0.w
              + e1.x*w1.x + e1.y*w1.y + e1.z*w1.z + e1.w*w1.w;
    float esq = e0.x*e0.x + e0.y*e0.y + e0.z*e0.z + e0.w*e0.w
              + e1.x*e1.x + e1.y*e1.y + e1.z*e1.z + e1.w*e1.w;
    float wsq = w0.x*w0.x + w0.y*w0.y + w0.z*w0.z + w0.w*w0.w
              + w1.x*w1.x + w1.y*w1.y + w1.z*w1.z + w1.w*w1.w;
    #pragma unroll
    for (int m = 32; m >= 1; m >>= 1) {
        dot += __shfl_xor(dot, m, 64);
        esq += __shfl_xor(esq, m, 64);
        wsq += __shfl_xor(wsq, m, 64);
    }
    if (lane == 0) {
        float t = dot * rsqrtf(esq + 1e-12f) * rsqrtf(wsq + 1e-12f);
        t = fminf(1.0f, fmaxf(-1.0f, t));
        float tc = fminf(1.0f - 1e-7f, fmaxf(-1.0f + 1e-7f, t));
        float marg = tc * COS_M - sqrtf(fmaxf(0.0f, 1.0f - tc * tc)) * SIN_M;
        float ft = (t > TH) ? marg : (t - MM_C);
        tp[p * 2]     = t;
        tp[p * 2 + 1] = ft;
    }
}

// ---------------- fused GEMM + exp-sum ----------------
// block: 256 thr = 4 waves (wm in {0,1} x wn in {0,1}); tile BM=64 x BN=128
// wave tile: 32 batch x 64 classes via 2x4 MFMAs of 16x16x32 per k-step
__global__ __launch_bounds__(256) void gemm_z(const float* __restrict__ W,
                                              const ushort* __restrict__ Eb,
                                              const float* __restrict__ invne,
                                              float* __restrict__ zpart) {
    const int lane = threadIdx.x & 63;
    const int w = threadIdx.x >> 6;
    const int wm = w >> 1, wn = w & 1;
    const int r16 = lane & 15, g = lane >> 4;
    const int bm = blockIdx.x * 64 + wm * 32;
    const int bn = blockIdx.y * 128 + wn * 64;

    f32x4 acc[2][4] = {};
    float ssq[4] = {0.f, 0.f, 0.f, 0.f};

    const ushort* a0 = Eb + (size_t)(bm + r16) * K_D + g * 8;
    const ushort* a1 = a0 + 16 * K_D;
    const float* wp[4];
    int cols[4];
    #pragma unroll
    for (int j = 0; j < 4; ++j) {
        int c = bn + j * 16 + r16;
        cols[j] = c;
        int cc = c < N_C ? c : N_C - 1;
        wp[j] = W + (size_t)cc * K_D + g * 8;
    }

    #pragma unroll 4
    for (int kk = 0; kk < K_D; kk += 32) {
        bf16x8 af0 = *(const bf16x8*)(a0 + kk);
        bf16x8 af1 = *(const bf16x8*)(a1 + kk);
        #pragma unroll
        for (int j = 0; j < 4; ++j) {
            float4 f0 = *(const float4*)(wp[j] + kk);
            float4 f1 = *(const float4*)(wp[j] + kk + 4);
            ssq[j] += f0.x*f0.x + f0.y*f0.y + f0.z*f0.z + f0.w*f0.w
                    + f1.x*f1.x + f1.y*f1.y + f1.z*f1.z + f1.w*f1.w;
            bf16x8 bf;
            bf[0] = f2bf(f0.x); bf[1] = f2bf(f0.y); bf[2] = f2bf(f0.z); bf[3] = f2bf(f0.w);
            bf[4] = f2bf(f1.x); bf[5] = f2bf(f1.y); bf[6] = f2bf(f1.z); bf[7] = f2bf(f1.w);
            acc[0][j] = __builtin_amdgcn_mfma_f32_16x16x32_bf16(af0, bf, acc[0][j], 0, 0, 0);
            acc[1][j] = __builtin_amdgcn_mfma_f32_16x16x32_bf16(af1, bf, acc[1][j], 0, 0, 0);
        }
    }

    // finish W row norms: lane (r16,g) holds 1/4 of row cols[j]; reduce over g
    float inw[4];
    #pragma unroll
    for (int j = 0; j < 4; ++j) {
        float s = ssq[j];
        s += __shfl_xor(s, 16, 64);
        s += __shfl_xor(s, 32, 64);
        inw[j] = rsqrtf(s + 1e-12f);
    }

    // epilogue: cos -> exp(64 cos - 64), per-row partial sums
    float rsum[2][4];
    #pragma unroll
    for (int i = 0; i < 2; ++i) {
        #pragma unroll
        for (int r = 0; r < 4; ++r) {
            int row = bm + i * 16 + g * 4 + r;
            float ine = invne[row];
            float s = 0.0f;
            #pragma unroll
            for (int j = 0; j < 4; ++j) {
                if (cols[j] < N_C) {
                    float cosv = acc[i][j][r] * inw[j] * ine;
                    cosv = fminf(1.0f, fmaxf(-1.0f, cosv));
                    s += expf(SCALE * cosv - 64.0f);
                }
            }
            rsum[i][r] = s;
        }
    }
    // reduce across the 16 lanes of each r16-group (same rows, different cols)
    #pragma unroll
    for (int m = 1; m < 16; m <<= 1) {
        #pragma unroll
        for (int i = 0; i < 2; ++i)
            #pragma unroll
            for (int r = 0; r < 4; ++r)
                rsum[i][r] += __shfl_xor(rsum[i][r], m, 64);
    }
    if (r16 == 0) {
        #pragma unroll
        for (int i = 0; i < 2; ++i)
            #pragma unroll
            for (int r = 0; r < 4; ++r) {
                int row = bm + i * 16 + g * 4 + r;
                zpart[(size_t)row * ZSTRIDE + blockIdx.y * 2 + wn] = rsum[i][r];
            }
    }
}

// ---------------- deterministic Z reduction ----------------
__global__ __launch_bounds__(256) void zreduce(const float* __restrict__ zpart,
                                               float* __restrict__ zrow) {
    int b = blockIdx.x;
    float s = 0.0f;
    for (int t = threadIdx.x; t < 2 * NCS; t += 256) s += zpart[(size_t)b * ZSTRIDE + t];
    __shared__ float red[256];
    red[threadIdx.x] = s;
    __syncthreads();
    for (int st = 128; st >= 1; st >>= 1) {
        if (threadIdx.x < st) red[threadIdx.x] += red[threadIdx.x + st];
        __syncthreads();
    }
    if (threadIdx.x == 0) zrow[b] = red[0];
}

// ---------------- final loss ----------------
__global__ __launch_bounds__(256) void final_kernel(const float* __restrict__ zrow,
                                                    const float* __restrict__ tp,
                                                    float* __restrict__ out) {
    int b = threadIdx.x;
    float Z = zrow[b];
    float lsum = 0.0f;
    #pragma unroll
    for (int j = 0; j < 3; ++j) {
        float t  = tp[(b * 3 + j) * 2];
        float ft = tp[(b * 3 + j) * 2 + 1];
        float S = Z - expf(SCALE * t - 64.0f) + expf(SCALE * ft - 64.0f);
        lsum += logf(S) + 64.0f - SCALE * ft;
    }
    __shared__ float red[256];
    red[b] = lsum;
    __syncthreads();
    for (int st = 128; st >= 1; st >>= 1) {
        if (b < st) red[b] += red[b + st];
        __syncthreads();
    }
    if (b == 0) out[0] = red[0] / 768.0f;
}

extern "C" void kernel_launch(void* const* d_in, const int* in_sizes, int n_in,
                              void* d_out, int out_size, void* d_ws, size_t ws_size,
                              hipStream_t stream) {
    const float* E = (const float*)d_in[0];
    const float* W = (const float*)d_in[1];
    const int*  LL = (const int*)d_in[2];
    char* ws = (char*)d_ws;
    float*  invne = (float*)(ws + OFF_INVNE);
    ushort* Eb    = (ushort*)(ws + OFF_EMB16);
    int*    lab3  = (int*)(ws + OFF_LAB);
    float*  tp    = (float*)(ws + OFF_T);
    float*  zpart = (float*)(ws + OFF_ZPART);
    float*  zrow  = (float*)(ws + OFF_ZROW);
    float*  out   = (float*)d_out;

    hipLaunchKernelGGL(prep_emb,      dim3(64),       dim3(256), 0, stream, E, Eb, invne);
    hipLaunchKernelGGL(labels_kernel, dim3(1),        dim3(256), 0, stream, LL, lab3);
    hipLaunchKernelGGL(target_kernel, dim3(192),      dim3(256), 0, stream, E, W, lab3, tp);
    hipLaunchKernelGGL(gemm_z,        dim3(4, NCS),   dim3(256), 0, stream, W, Eb, invne, zpart);
    hipLaunchKernelGGL(zreduce,       dim3(256),      dim3(256), 0, stream, zpart, zrow);
    hipLaunchKernelGGL(final_kernel,  dim3(1),        dim3(256), 0, stream, zrow, tp, out);
}

// Round 2
// 180.532 us; speedup vs baseline: 1.4437x; 1.4437x over previous
//
#include <hip/hip_runtime.h>
#include <hip/hip_bf16.h>
#include <stdint.h>

#define M_B 256
#define K_D 512
#define N_C 100000
#define SCALE 64.0f

// margin constants (double-precision derived)
#define COS_M 0.87758256189037271612f
#define SIN_M 0.47942553860420300027f
#define TH   (-0.87758256189037271612f)
#define MM_C  0.23971276930210150013f

typedef __attribute__((ext_vector_type(8))) short bf16x8;
typedef __attribute__((ext_vector_type(4))) float f32x4;

// ws byte offsets (total 1,869,824 B — within proven ws_size >= 1,879,040)
#define OFF_INVNE 0          // 256 f = 1 KB
#define OFF_EMB16 1024       // 256*512 ushort = 256 KB
#define OFF_TP    263168     // 768*2 f = 6 KB
#define OFF_ZPART 269312     // 1563*256 f = 1,600,512 B

#define NCB 1563             // ceil(100000/64)

__device__ __forceinline__ short f2bf(float f) {
    __hip_bfloat16 h = __float2bfloat16(f);
    return __builtin_bit_cast(short, h);
}

__device__ __forceinline__ void async16(const float* src, float* dst) {
    __builtin_amdgcn_global_load_lds(
        (const __attribute__((address_space(1))) void*)src,
        (__attribute__((address_space(3))) void*)dst,
        16, 0, 0);
}

// ---------------- prep_emb: raw bf16 copy of E + inv row norms ----------------
__global__ __launch_bounds__(256) void prep_emb(const float* __restrict__ E,
                                                ushort* __restrict__ Eb,
                                                float* __restrict__ invne) {
    int w = threadIdx.x >> 6, lane = threadIdx.x & 63;
    int row = blockIdx.x * 4 + w;
    const float4* src = (const float4*)(E + row * K_D);
    float4 v0 = src[lane];
    float4 v1 = src[lane + 64];
    float ss = v0.x*v0.x + v0.y*v0.y + v0.z*v0.z + v0.w*v0.w
             + v1.x*v1.x + v1.y*v1.y + v1.z*v1.z + v1.w*v1.w;
    #pragma unroll
    for (int m = 32; m >= 1; m >>= 1) ss += __shfl_xor(ss, m, 64);
    ushort4 o0, o1;
    o0.x = (ushort)f2bf(v0.x); o0.y = (ushort)f2bf(v0.y);
    o0.z = (ushort)f2bf(v0.z); o0.w = (ushort)f2bf(v0.w);
    o1.x = (ushort)f2bf(v1.x); o1.y = (ushort)f2bf(v1.y);
    o1.z = (ushort)f2bf(v1.z); o1.w = (ushort)f2bf(v1.w);
    ((ushort4*)(Eb + row * K_D))[lane]      = o0;
    ((ushort4*)(Eb + row * K_D))[lane + 64] = o1;
    if (lane == 0) invne[row] = rsqrtf(ss + 1e-12f);
}

// ---------------- threefry2x32 (JAX, key=42) ----------------
__device__ __forceinline__ void threefry(uint32_t x0, uint32_t x1, uint32_t& o0, uint32_t& o1) {
    const uint32_t k0 = 0u, k1 = 42u;
    const uint32_t k2 = k0 ^ k1 ^ 0x1BD11BDAu;
    const uint32_t ks[3] = {k0, k1, k2};
    x0 += k0; x1 += k1;
    const int rot0[4] = {13, 15, 26, 6};
    const int rot1[4] = {17, 29, 16, 24};
    #pragma unroll
    for (int grp = 0; grp < 5; ++grp) {
        const int* r = (grp & 1) ? rot1 : rot0;
        #pragma unroll
        for (int i = 0; i < 4; ++i) {
            x0 += x1;
            x1 = (x1 << r[i]) | (x1 >> (32 - r[i]));
            x1 ^= x0;
        }
        x0 += ks[(grp + 1) % 3];
        x1 += ks[(grp + 2) % 3] + (uint32_t)(grp + 1);
    }
    o0 = x0; o1 = x1;
}

// ---------------- targets: inline label shuffle + precise fp32 cosine + margin ----------------
__global__ __launch_bounds__(256) void target_kernel(const float* __restrict__ E,
                                                     const float* __restrict__ W,
                                                     const int* __restrict__ ll,
                                                     float* __restrict__ tp) {
    int w = threadIdx.x >> 6, lane = threadIdx.x & 63;
    int p = blockIdx.x * 4 + w;      // 768 pairs
    int b = p / 3;
    int jj = p - b * 3;
    // recompute the label selection for (b, jj)
    float u[8];
    #pragma unroll
    for (int j = 0; j < 8; ++j) {
        int n = b * 8 + j;
        uint32_t x0, x1, o0, o1;
        if (n < 1024) { x0 = (uint32_t)n; x1 = (uint32_t)(n + 1024); }
        else          { x0 = (uint32_t)(n - 1024); x1 = (uint32_t)n; }
        threefry(x0, x1, o0, o1);
        uint32_t bits = (n < 1024) ? o0 : o1;
        uint32_t fb = (bits >> 9) | 0x3F800000u;
        u[j] = __builtin_bit_cast(float, fb) - 1.0f;
    }
    bool used[8] = {false,false,false,false,false,false,false,false};
    int sel = 0;
    for (int s = 0; s <= jj; ++s) {
        float bv = 2.0f; int bi = 0;
        for (int i = 0; i < 8; ++i)
            if (!used[i] && u[i] < bv) { bv = u[i]; bi = i; }
        used[bi] = true;
        sel = bi;
    }
    int c = ll[b * 8 + sel];

    const float4* ep = (const float4*)(E + (size_t)b * K_D);
    const float4* wp = (const float4*)(W + (size_t)c * K_D);
    float4 e0 = ep[lane], e1 = ep[lane + 64];
    float4 w0 = wp[lane], w1 = wp[lane + 64];
    float dot = e0.x*w0.x + e0.y*w0.y + e0.z*w0.z + e0.w*w0.w
              + e1.x*w1.x + e1.y*w1.y + e1.z*w1.z + e1.w*w1.w;
    float esq = e0.x*e0.x + e0.y*e0.y + e0.z*e0.z + e0.w*e0.w
              + e1.x*e1.x + e1.y*e1.y + e1.z*e1.z + e1.w*e1.w;
    float wsq = w0.x*w0.x + w0.y*w0.y + w0.z*w0.z + w0.w*w0.w
              + w1.x*w1.x + w1.y*w1.y + w1.z*w1.z + w1.w*w1.w;
    #pragma unroll
    for (int m = 32; m >= 1; m >>= 1) {
        dot += __shfl_xor(dot, m, 64);
        esq += __shfl_xor(esq, m, 64);
        wsq += __shfl_xor(wsq, m, 64);
    }
    if (lane == 0) {
        float t = dot * rsqrtf(esq + 1e-12f) * rsqrtf(wsq + 1e-12f);
        t = fminf(1.0f, fmaxf(-1.0f, t));
        float tc = fminf(1.0f - 1e-7f, fmaxf(-1.0f + 1e-7f, t));
        float marg = tc * COS_M - sqrtf(fmaxf(0.0f, 1.0f - tc * tc)) * SIN_M;
        float ft = (t > TH) ? marg : (t - MM_C);
        tp[p * 2]     = t;
        tp[p * 2 + 1] = ft;
    }
}

// ---------------- fused GEMM + exp-sum, W read once ----------------
// grid 1563 x block 256 (4 waves, 2M x 2N). Tile: M=256 (all batch) x N=64.
// W tile 64x32 fp32 staged async into dbuf LDS with XOR-swizzled global source.
__global__ __launch_bounds__(256, 3) void gemm_z(const float* __restrict__ W,
                                                 const ushort* __restrict__ Eb,
                                                 const float* __restrict__ invne,
                                                 float* __restrict__ zpart) {
    __shared__ float Bl[2][2048];   // 2 x 8 KB: [64 rows][8 chunks of 4 f], swizzled
    __shared__ float inw_lds[64];
    __shared__ float ine_lds[256];
    __shared__ float zred[2][256];

    const int tid  = threadIdx.x;
    const int lane = tid & 63, wv = tid >> 6;
    const int wm = wv >> 1, wn = wv & 1;
    const int r16 = lane & 15, g = lane >> 4;
    const int bx = blockIdx.x;
    const int c0 = bx * 64;

    // staging source addresses (2 issues of 1 KB per wave; dest is linear)
    // chunk n = i*256 + wv*64 + lane ; row = n>>3 ; kc_phys = lane&7
    // stored-logical chunk = kc_phys ^ (row&7), row&7 == lane>>3
    const int kc_log = (lane & 7) ^ (lane >> 3);
    int row0 = wv * 8 + (lane >> 3);
    int row1 = row0 + 32;
    int cr0 = c0 + row0; if (cr0 >= N_C) cr0 = N_C - 1;
    int cr1 = c0 + row1; if (cr1 >= N_C) cr1 = N_C - 1;
    const float* s0 = W + (size_t)cr0 * K_D + kc_log * 4;
    const float* s1 = W + (size_t)cr1 * K_D + kc_log * 4;

    ine_lds[tid] = invne[tid];

    const ushort* Ab = Eb + (size_t)(wm * 128 + r16) * K_D + g * 8;

    f32x4 acc[8][2] = {};
    float ssq[2] = {0.f, 0.f};

    // prologue: stage tile 0
    async16(s0, &Bl[0][wv * 256]);
    async16(s1, &Bl[0][1024 + wv * 256]);
    __syncthreads();

    for (int kt = 0; kt < 16; ++kt) {
        const int cur = kt & 1;
        if (kt < 15) {
            async16(s0 + (kt + 1) * 32, &Bl[cur ^ 1][wv * 256]);
            async16(s1 + (kt + 1) * 32, &Bl[cur ^ 1][1024 + wv * 256]);
        }
        const int kk = kt * 32;
        bf16x8 a[8];
        #pragma unroll
        for (int m = 0; m < 8; ++m)
            a[m] = *(const bf16x8*)(Ab + (size_t)m * (16 * K_D) + kk);
        #pragma unroll
        for (int j = 0; j < 2; ++j) {
            const int crl = wn * 32 + j * 16 + r16;   // local class row 0..63
            const int mrow = crl & 7;
            const float* bp = &Bl[cur][crl * 32];
            float4 f0 = *(const float4*)(bp + (((2 * g)     ^ mrow) << 2));
            float4 f1 = *(const float4*)(bp + (((2 * g + 1) ^ mrow) << 2));
            if (wm == 0)
                ssq[j] += f0.x*f0.x + f0.y*f0.y + f0.z*f0.z + f0.w*f0.w
                        + f1.x*f1.x + f1.y*f1.y + f1.z*f1.z + f1.w*f1.w;
            bf16x8 bv;
            bv[0] = f2bf(f0.x); bv[1] = f2bf(f0.y); bv[2] = f2bf(f0.z); bv[3] = f2bf(f0.w);
            bv[4] = f2bf(f1.x); bv[5] = f2bf(f1.y); bv[6] = f2bf(f1.z); bv[7] = f2bf(f1.w);
            #pragma unroll
            for (int m = 0; m < 8; ++m)
                acc[m][j] = __builtin_amdgcn_mfma_f32_16x16x32_bf16(a[m], bv, acc[m][j], 0, 0, 0);
        }
        __syncthreads();
    }

    // W row inverse norms (computed by wm==0 waves, shared via LDS)
    #pragma unroll
    for (int j = 0; j < 2; ++j) {
        float s = ssq[j];
        s += __shfl_xor(s, 16, 64);
        s += __shfl_xor(s, 32, 64);
        if (wm == 0 && g == 0) inw_lds[wn * 32 + j * 16 + r16] = rsqrtf(s + 1e-12f);
    }
    __syncthreads();

    // epilogue: cos -> exp(64 cos - 64), reduce to per-row partials
    #pragma unroll
    for (int m = 0; m < 8; ++m) {
        #pragma unroll
        for (int r = 0; r < 4; ++r) {
            const int grow = wm * 128 + m * 16 + g * 4 + r;   // local batch row
            const float ine = ine_lds[grow];
            float s = 0.f;
            #pragma unroll
            for (int j = 0; j < 2; ++j) {
                const int cl = wn * 32 + j * 16 + r16;
                const int gcol = c0 + cl;
                float cosv = acc[m][j][r] * inw_lds[cl] * ine;
                cosv = fminf(1.0f, fmaxf(-1.0f, cosv));
                float e = __expf(SCALE * cosv - 64.0f);
                if (gcol < N_C) s += e;
            }
            s += __shfl_xor(s, 1, 64);
            s += __shfl_xor(s, 2, 64);
            s += __shfl_xor(s, 4, 64);
            s += __shfl_xor(s, 8, 64);
            if (r16 == ((m * 4 + r) & 15)) zred[wn][grow] = s;
        }
    }
    __syncthreads();
    zpart[(size_t)bx * 256 + tid] = zred[0][tid] + zred[1][tid];
}

// ---------------- finalize: Z row-sum + loss ----------------
__global__ __launch_bounds__(256) void finalize(const float* __restrict__ zpart,
                                                const float* __restrict__ tp,
                                                float* __restrict__ out) {
    const int b = threadIdx.x;
    float z0 = 0.f, z1 = 0.f, z2 = 0.f, z3 = 0.f;
    int bx = 0;
    for (; bx + 4 <= NCB; bx += 4) {
        z0 += zpart[(size_t)(bx + 0) * 256 + b];
        z1 += zpart[(size_t)(bx + 1) * 256 + b];
        z2 += zpart[(size_t)(bx + 2) * 256 + b];
        z3 += zpart[(size_t)(bx + 3) * 256 + b];
    }
    for (; bx < NCB; ++bx) z0 += zpart[(size_t)bx * 256 + b];
    const float Z = (z0 + z1) + (z2 + z3);
    float lsum = 0.f;
    #pragma unroll
    for (int j = 0; j < 3; ++j) {
        float t  = tp[(b * 3 + j) * 2];
        float ft = tp[(b * 3 + j) * 2 + 1];
        float S = Z - expf(SCALE * t - 64.0f) + expf(SCALE * ft - 64.0f);
        lsum += logf(S) + 64.0f - SCALE * ft;
    }
    __shared__ float red[256];
    red[b] = lsum;
    __syncthreads();
    for (int st = 128; st >= 1; st >>= 1) {
        if (b < st) red[b] += red[b + st];
        __syncthreads();
    }
    if (b == 0) out[0] = red[0] / 768.0f;
}

extern "C" void kernel_launch(void* const* d_in, const int* in_sizes, int n_in,
                              void* d_out, int out_size, void* d_ws, size_t ws_size,
                              hipStream_t stream) {
    const float* E = (const float*)d_in[0];
    const float* W = (const float*)d_in[1];
    const int*  LL = (const int*)d_in[2];
    char* ws = (char*)d_ws;
    float*  invne = (float*)(ws + OFF_INVNE);
    ushort* Eb    = (ushort*)(ws + OFF_EMB16);
    float*  tp    = (float*)(ws + OFF_TP);
    float*  zpart = (float*)(ws + OFF_ZPART);
    float*  out   = (float*)d_out;

    hipLaunchKernelGGL(prep_emb,      dim3(64),   dim3(256), 0, stream, E, Eb, invne);
    hipLaunchKernelGGL(target_kernel, dim3(192),  dim3(256), 0, stream, E, W, LL, tp);
    hipLaunchKernelGGL(gemm_z,        dim3(NCB),  dim3(256), 0, stream, W, Eb, invne, zpart);
    hipLaunchKernelGGL(finalize,      dim3(1),    dim3(256), 0, stream, zpart, tp, out);
}

// Round 3
// 100.484 us; speedup vs baseline: 2.5939x; 1.7966x over previous
//
#include <hip/hip_runtime.h>
#include <hip/hip_bf16.h>
#include <stdint.h>

#define K_D 512
#define N_C 100000
#define SCALE 64.0f

// margin constants (double-precision derived)
#define COS_M 0.87758256189037271612f
#define SIN_M 0.47942553860420300027f
#define TH   (-0.87758256189037271612f)
#define MM_C  0.23971276930210150013f

typedef __attribute__((ext_vector_type(8))) short bf16x8;
typedef __attribute__((ext_vector_type(4))) float f32x4;

#define GZ_BLOCKS 1250   // x 5 chunks x 16 classes = 100,000 exactly
#define CHUNKS_PB 5
#define ZSTRIDE 1280

// ws byte offsets (max 1,581,056 — within proven ws capacity 1,879,040)
#define OFF_INVNE 0          // 256 f
#define OFF_EMB   1024       // 256*512 ushorts = 262144 (fragment-ordered)
#define OFF_TP    263168     // 768*2 f
#define OFF_ZROW  269312     // 256 f
#define OFF_ZPART 270336     // 256*1280 f = 1,310,720

__device__ __forceinline__ ushort f2bf(float f) {
    __hip_bfloat16 h = __float2bfloat16(f);
    return __builtin_bit_cast(ushort, h);
}

__device__ __forceinline__ void async16(const float* src, float* dst) {
    __builtin_amdgcn_global_load_lds(
        (const __attribute__((address_space(1))) void*)src,
        (__attribute__((address_space(3))) void*)dst,
        16, 0, 0);
}

// ---------------- prep_emb: fragment-ordered bf16 copy of E + inv row norms ----
// Ebf layout: slot = ((row>>4)*16 + kstep)*64 + (row&15) + g*16, 8 ushorts per slot
// so gemm's A-load for (mtile, kstep) is one coalesced b128 per lane.
__global__ __launch_bounds__(256) void prep_emb(const float* __restrict__ E,
                                                ushort* __restrict__ Ebf,
                                                float* __restrict__ invne) {
    int w = threadIdx.x >> 6, lane = threadIdx.x & 63;
    int row = blockIdx.x * 4 + w;
    const float4* src = (const float4*)(E + (size_t)row * K_D);
    float4 a = src[2 * lane];          // k = lane*8 .. +4
    float4 b = src[2 * lane + 1];      // k = lane*8+4 .. +8
    float ss = a.x*a.x + a.y*a.y + a.z*a.z + a.w*a.w
             + b.x*b.x + b.y*b.y + b.z*b.z + b.w*b.w;
    #pragma unroll
    for (int m = 32; m >= 1; m >>= 1) ss += __shfl_xor(ss, m, 64);
    uint4 pk;
    pk.x = (uint32_t)f2bf(a.x) | ((uint32_t)f2bf(a.y) << 16);
    pk.y = (uint32_t)f2bf(a.z) | ((uint32_t)f2bf(a.w) << 16);
    pk.z = (uint32_t)f2bf(b.x) | ((uint32_t)f2bf(b.y) << 16);
    pk.w = (uint32_t)f2bf(b.z) | ((uint32_t)f2bf(b.w) << 16);
    const int kstep = lane >> 2, gg = lane & 3;
    const size_t slot = ((size_t)(row >> 4) * 16 + kstep) * 64 + (row & 15) + (gg << 4);
    ((uint4*)Ebf)[slot] = pk;
    if (lane == 0) invne[row] = rsqrtf(ss + 1e-12f);
}

// ---------------- threefry2x32 (JAX, key=42) ----------------
__device__ __forceinline__ void threefry(uint32_t x0, uint32_t x1, uint32_t& o0, uint32_t& o1) {
    const uint32_t k0 = 0u, k1 = 42u;
    const uint32_t k2 = k0 ^ k1 ^ 0x1BD11BDAu;
    const uint32_t ks[3] = {k0, k1, k2};
    x0 += k0; x1 += k1;
    const int rot0[4] = {13, 15, 26, 6};
    const int rot1[4] = {17, 29, 16, 24};
    #pragma unroll
    for (int grp = 0; grp < 5; ++grp) {
        const int* r = (grp & 1) ? rot1 : rot0;
        #pragma unroll
        for (int i = 0; i < 4; ++i) {
            x0 += x1;
            x1 = (x1 << r[i]) | (x1 >> (32 - r[i]));
            x1 ^= x0;
        }
        x0 += ks[(grp + 1) % 3];
        x1 += ks[(grp + 2) % 3] + (uint32_t)(grp + 1);
    }
    o0 = x0; o1 = x1;
}

// ---------------- targets: inline label shuffle + precise fp32 cosine + margin ----
__global__ __launch_bounds__(256) void target_kernel(const float* __restrict__ E,
                                                     const float* __restrict__ W,
                                                     const int* __restrict__ ll,
                                                     float* __restrict__ tp) {
    int w = threadIdx.x >> 6, lane = threadIdx.x & 63;
    int p = blockIdx.x * 4 + w;      // 768 pairs
    int b = p / 3;
    int jj = p - b * 3;
    float u[8];
    #pragma unroll
    for (int j = 0; j < 8; ++j) {
        int n = b * 8 + j;
        uint32_t x0, x1, o0, o1;
        if (n < 1024) { x0 = (uint32_t)n; x1 = (uint32_t)(n + 1024); }
        else          { x0 = (uint32_t)(n - 1024); x1 = (uint32_t)n; }
        threefry(x0, x1, o0, o1);
        uint32_t bits = (n < 1024) ? o0 : o1;
        uint32_t fb = (bits >> 9) | 0x3F800000u;
        u[j] = __builtin_bit_cast(float, fb) - 1.0f;
    }
    bool used[8] = {false,false,false,false,false,false,false,false};
    int sel = 0;
    for (int s = 0; s <= jj; ++s) {
        float bv = 2.0f; int bi = 0;
        for (int i = 0; i < 8; ++i)
            if (!used[i] && u[i] < bv) { bv = u[i]; bi = i; }
        used[bi] = true;
        sel = bi;
    }
    int c = ll[b * 8 + sel];

    const float4* ep = (const float4*)(E + (size_t)b * K_D);
    const float4* wp = (const float4*)(W + (size_t)c * K_D);
    float4 e0 = ep[lane], e1 = ep[lane + 64];
    float4 w0 = wp[lane], w1 = wp[lane + 64];
    float dot = e0.x*w0.x + e0.y*w0.y + e0.z*w0.z + e0.w*w0.w
              + e1.x*w1.x + e1.y*w1.y + e1.z*w1.z + e1.w*w1.w;
    float esq = e0.x*e0.x + e0.y*e0.y + e0.z*e0.z + e0.w*e0.w
              + e1.x*e1.x + e1.y*e1.y + e1.z*e1.z + e1.w*e1.w;
    float wsq = w0.x*w0.x + w0.y*w0.y + w0.z*w0.z + w0.w*w0.w
              + w1.x*w1.x + w1.y*w1.y + w1.z*w1.z + w1.w*w1.w;
    #pragma unroll
    for (int m = 32; m >= 1; m >>= 1) {
        dot += __shfl_xor(dot, m, 64);
        esq += __shfl_xor(esq, m, 64);
        wsq += __shfl_xor(wsq, m, 64);
    }
    if (lane == 0) {
        float t = dot * rsqrtf(esq + 1e-12f) * rsqrtf(wsq + 1e-12f);
        t = fminf(1.0f, fmaxf(-1.0f, t));
        float tc = fminf(1.0f - 1e-7f, fmaxf(-1.0f + 1e-7f, t));
        float marg = tc * COS_M - sqrtf(fmaxf(0.0f, 1.0f - tc * tc)) * SIN_M;
        float ft = (t > TH) ? marg : (t - MM_C);
        tp[p * 2]     = t;
        tp[p * 2 + 1] = ft;
    }
}

// ---------------- fused GEMM + exp-sum: contiguous full-row W streaming ----------
// 512 thr (8 waves); block owns 80 classes (5 chunks of 16). Per chunk: stage
// 16 full W rows (32 KB) via 1KB-contiguous DMA bursts, then full K=512 MFMA
// pass (256 MFMAs/block) before the drain barrier -> latency fully hidden.
__global__ __launch_bounds__(512, 4) void gemm_z(const float* __restrict__ W,
                                                 const ushort* __restrict__ Ebf,
                                                 const float* __restrict__ invne,
                                                 float* __restrict__ zpart) {
    __shared__ float Bbuf[2][16 * 512];   // 2 x 32 KB, 16B-grain XOR swizzled
    __shared__ float ine_lds[256];

    const int tid  = threadIdx.x;
    const int lane = tid & 63, wv = tid >> 6;       // wv 0..7
    const int r16  = lane & 15, g = lane >> 4;
    const int s    = r16 & 7;
    const int bx   = blockIdx.x;
    const int cbase = bx * (16 * CHUNKS_PB);

    if (tid < 256) ine_lds[tid] = invne[tid];

    // stage chunk ch into buffer b: wave wv stages rows wv*2, wv*2+1.
    // LDS dest linear (lane*16B); global source inverse-XOR-swizzled (rule #21).
    #define STAGE(ch, b)                                                          \
        {                                                                         \
            _Pragma("unroll")                                                     \
            for (int rr = 0; rr < 2; ++rr) {                                      \
                const int r = wv * 2 + rr;                                        \
                const float* src = W + (size_t)(cbase + (ch) * 16 + r) * K_D;     \
                _Pragma("unroll")                                                 \
                for (int hb = 0; hb < 2; ++hb) {                                  \
                    const int hp = hb * 64 + lane;                                \
                    async16(src + ((hp ^ (r & 7)) << 2),                          \
                            &Bbuf[b][r * 512 + hb * 256]);                        \
                }                                                                 \
            }                                                                     \
        }

    STAGE(0, 0);
    __syncthreads();

    float zacc[2][4] = {};

    for (int ch = 0; ch < CHUNKS_PB; ++ch) {
        const int cur = ch & 1;
        if (ch + 1 < CHUNKS_PB) STAGE(ch + 1, cur ^ 1);

        f32x4 acc0 = {}, acc1 = {};
        float ssq = 0.f;
        const float4* bp = (const float4*)&Bbuf[cur][r16 * 512];
        const ushort* ap0 = Ebf + ((size_t)(wv * 2 + 0) * 16) * 64 * 8 + lane * 8;
        const ushort* ap1 = Ebf + ((size_t)(wv * 2 + 1) * 16) * 64 * 8 + lane * 8;

        #pragma unroll 4
        for (int ks = 0; ks < 16; ++ks) {
            bf16x8 a0 = *(const bf16x8*)(ap0 + (size_t)ks * 512);
            bf16x8 a1 = *(const bf16x8*)(ap1 + (size_t)ks * 512);
            const int h = ks * 8 + g * 2;
            float4 f0 = bp[(h)     ^ s];
            float4 f1 = bp[(h + 1) ^ s];
            ssq += f0.x*f0.x + f0.y*f0.y + f0.z*f0.z + f0.w*f0.w
                 + f1.x*f1.x + f1.y*f1.y + f1.z*f1.z + f1.w*f1.w;
            bf16x8 bv;
            bv[0] = (short)f2bf(f0.x); bv[1] = (short)f2bf(f0.y);
            bv[2] = (short)f2bf(f0.z); bv[3] = (short)f2bf(f0.w);
            bv[4] = (short)f2bf(f1.x); bv[5] = (short)f2bf(f1.y);
            bv[6] = (short)f2bf(f1.z); bv[7] = (short)f2bf(f1.w);
            acc0 = __builtin_amdgcn_mfma_f32_16x16x32_bf16(a0, bv, acc0, 0, 0, 0);
            acc1 = __builtin_amdgcn_mfma_f32_16x16x32_bf16(a1, bv, acc1, 0, 0, 0);
        }

        // class inverse norm (class = cbase + ch*16 + r16): reduce ssq over g
        float sr = ssq;
        sr += __shfl_xor(sr, 16, 64);
        sr += __shfl_xor(sr, 32, 64);
        const float inw = rsqrtf(sr + 1e-12f);

        #pragma unroll
        for (int i = 0; i < 4; ++i) {
            const int row0 = (wv * 2 + 0) * 16 + g * 4 + i;
            const int row1 = (wv * 2 + 1) * 16 + g * 4 + i;
            float c0 = acc0[i] * inw * ine_lds[row0];
            float c1 = acc1[i] * inw * ine_lds[row1];
            c0 = fminf(1.0f, fmaxf(-1.0f, c0));
            c1 = fminf(1.0f, fmaxf(-1.0f, c1));
            zacc[0][i] += __expf(SCALE * c0 - 64.0f);
            zacc[1][i] += __expf(SCALE * c1 - 64.0f);
        }
        __syncthreads();   // drains next-chunk DMA; protects buffer reuse
    }

    // reduce zacc over the 16 classes (r16 lanes), write zpart[row][bx]
    #pragma unroll
    for (int mi = 0; mi < 2; ++mi)
        #pragma unroll
        for (int i = 0; i < 4; ++i) {
            float v = zacc[mi][i];
            v += __shfl_xor(v, 1, 64);
            v += __shfl_xor(v, 2, 64);
            v += __shfl_xor(v, 4, 64);
            v += __shfl_xor(v, 8, 64);
            if (r16 == 0) {
                const int row = (wv * 2 + mi) * 16 + g * 4 + i;
                zpart[(size_t)row * ZSTRIDE + bx] = v;
            }
        }
}

// ---------------- per-row Z reduction (coalesced) ----------------
__global__ __launch_bounds__(256) void zrow_kernel(const float* __restrict__ zpart,
                                                   float* __restrict__ zrow) {
    const int b = blockIdx.x;
    float sum = 0.f;
    for (int t = threadIdx.x; t < GZ_BLOCKS; t += 256)
        sum += zpart[(size_t)b * ZSTRIDE + t];
    __shared__ float red[256];
    red[threadIdx.x] = sum;
    __syncthreads();
    for (int st = 128; st >= 1; st >>= 1) {
        if (threadIdx.x < st) red[threadIdx.x] += red[threadIdx.x + st];
        __syncthreads();
    }
    if (threadIdx.x == 0) zrow[b] = red[0];
}

// ---------------- final loss ----------------
__global__ __launch_bounds__(256) void loss_kernel(const float* __restrict__ zrow,
                                                   const float* __restrict__ tp,
                                                   float* __restrict__ out) {
    const int b = threadIdx.x;
    const float Z = zrow[b];
    float lsum = 0.f;
    #pragma unroll
    for (int j = 0; j < 3; ++j) {
        float t  = tp[(b * 3 + j) * 2];
        float ft = tp[(b * 3 + j) * 2 + 1];
        float S = Z - expf(SCALE * t - 64.0f) + expf(SCALE * ft - 64.0f);
        lsum += logf(S) + 64.0f - SCALE * ft;
    }
    __shared__ float red[256];
    red[b] = lsum;
    __syncthreads();
    for (int st = 128; st >= 1; st >>= 1) {
        if (b < st) red[b] += red[b + st];
        __syncthreads();
    }
    if (b == 0) out[0] = red[0] / 768.0f;
}

extern "C" void kernel_launch(void* const* d_in, const int* in_sizes, int n_in,
                              void* d_out, int out_size, void* d_ws, size_t ws_size,
                              hipStream_t stream) {
    const float* E = (const float*)d_in[0];
    const float* W = (const float*)d_in[1];
    const int*  LL = (const int*)d_in[2];
    char* ws = (char*)d_ws;
    float*  invne = (float*)(ws + OFF_INVNE);
    ushort* Ebf   = (ushort*)(ws + OFF_EMB);
    float*  tp    = (float*)(ws + OFF_TP);
    float*  zrow  = (float*)(ws + OFF_ZROW);
    float*  zpart = (float*)(ws + OFF_ZPART);
    float*  out   = (float*)d_out;

    hipLaunchKernelGGL(prep_emb,      dim3(64),        dim3(256), 0, stream, E, Ebf, invne);
    hipLaunchKernelGGL(target_kernel, dim3(192),       dim3(256), 0, stream, E, W, LL, tp);
    hipLaunchKernelGGL(gemm_z,        dim3(GZ_BLOCKS), dim3(512), 0, stream, W, Ebf, invne, zpart);
    hipLaunchKernelGGL(zrow_kernel,   dim3(256),       dim3(256), 0, stream, zpart, zrow);
    hipLaunchKernelGGL(loss_kernel,   dim3(1),         dim3(256), 0, stream, zrow, tp, out);
}